// Round 4
// baseline (144.925 us; speedup 1.0000x reference)
//
#include <hip/hip_runtime.h>
#include <hip/hip_cooperative_groups.h>

namespace cg = cooperative_groups;

#define NN 256     // Preisach mesh size
#define TT 16      // outputs (steps) per chunk; G = ceil(M/TT) = 250 for M=4000

__device__ __forceinline__ float softplus_f(float x) {
    if (x > 20.0f) return x;
    return log1pf(expf(x));
}

// mode: 0 = cooperative fused (grid.sync between phases)
//       1 = phase-1 only (fallback), 2 = phase-2 only (fallback)
// Phase 1: blocks [0,NN) prefix rows of dens (transposed store);
//          blocks [NN,NN+G) chunk tables (records kept in LDS + UDt row).
// Phase 2: blocks [NN,NN+G) (or [0,G) standalone): ILP-32 carry scan over
//          prior chunk tables + 16-step walk + reduce -> out.
__global__ void __launch_bounds__(256, 2)
kMain(const float* __restrict__ h_g, const float* __restrict__ raw,
      float* __restrict__ out, int M, int G,
      float* __restrict__ PrefT, float* __restrict__ RowTot,
      int* __restrict__ steps_g, unsigned int* __restrict__ UDt, int mode)
{
    __shared__ float xs[NN];
    __shared__ float hh[TT + 1];
    __shared__ int   dd[TT + 1];
    __shared__ int   rec_s[TT + 1];        // persists across grid.sync in fused mode
    __shared__ int   Dv[NN];
    __shared__ float red[4 * (TT + 2)];
    __shared__ float tot[TT + 2];
    __shared__ float wsum[4];

    const int b = blockIdx.x, tid = threadIdx.x;
    const bool fused = (mode == 0);

    // ---------------- Phase 1 ----------------
    if (mode != 2) {
        if (b < NN) {
            // per-row prefix sums of dens = softplus(raw) on the lower triangle.
            // Intra-wave shuffle scan, cross-wave via wave totals (verified r3).
            float x = 0.0f;
            if (tid <= b) x = softplus_f(raw[b * (b + 1) / 2 + tid]);
            int lane = tid & 63, wv = tid >> 6;
            #pragma unroll
            for (int off = 1; off <= 32; off <<= 1) {
                float y = __shfl_up(x, off, 64);
                if (lane >= off) x += y;
            }
            if (lane == 63) wsum[wv] = x;
            __syncthreads();
            float add = 0.0f;
            if (wv > 0) add += wsum[0];
            if (wv > 1) add += wsum[1];
            if (wv > 2) add += wsum[2];
            x += add;
            PrefT[(tid + 1) * NN + b] = x;         // PrefT[k][i], k=0..256
            if (tid == 0)      PrefT[b] = 0.0f;
            if (tid == NN - 1) RowTot[b] = x;
        } else {
            int c  = b - NN;                        // chunk id, < G by grid sizing
            int t0 = c * TT;
            int Tb = min(TT, M - t0);
            xs[tid] = (float)((double)tid / 255.0); // np.linspace(0,1,256) f64->f32
            if (tid < TT) rec_s[1 + tid] = 0;
            __syncthreads();
            if (tid < Tb) {
                int tau = t0 + 1 + tid;
                float cur  = (h_g[tau - 1] + 1.0f) * 0.5f;
                float prev = (tau == 1) ? 1.0f : (h_g[tau - 2] + 1.0f) * 0.5f;
                int d = (cur > prev) ? 2 : ((cur < prev) ? 0 : 1);
                int lo = 0, hi = NN;                // ih = #{x < cur}
                while (lo < hi) { int m = (lo + hi) >> 1; if (xs[m] < cur) lo = m + 1; else hi = m; }
                int ih = lo;
                lo = 0; hi = NN;                    // jh = #{x <= cur}
                while (lo < hi) { int m = (lo + hi) >> 1; if (xs[m] <= cur) lo = m + 1; else hi = m; }
                int jh = lo;
                hh[1 + tid] = cur;
                dd[1 + tid] = d - 1;
                int rec = d | (ih << 2) | (jh << 11);
                rec_s[1 + tid] = rec;
                if (mode == 1) steps_g[tau] = rec;  // only needed for fallback phase 2
            }
            __syncthreads();
            float xi = xs[tid];
            int Ue = 0, De = 0;                     // absolute tau+1, 0 = none
            for (int k = 1; k <= Tb; ++k) {
                float hv = hh[k]; int d = dd[k];
                if (d > 0 && hv > xi) Ue = t0 + k + 1;
                if (d < 0 && hv < xi) De = t0 + k + 1;
            }
            UDt[c * NN + tid] = (unsigned)Ue | ((unsigned)De << 16);  // chunk-major
        }
    }

    if (fused) cg::this_grid().sync();
    if (mode == 1) return;

    // ---------------- Phase 2 ----------------
    int c;
    if (fused) { if (b < NN) return; c = b - NN; }
    else       { c = b; }
    int t0 = c * TT;
    int Tb = min(TT, M - t0);

    if (mode == 2) {                                // standalone: reload records
        if (tid < TT) rec_s[1 + tid] = (tid < Tb) ? steps_g[t0 + 1 + tid] : 0;
        __syncthreads();
    }

    float RT = RowTot[tid];

    // carry-in: virtual tau=0 step (h = 1.0) + max over prior chunk tables
    float hsM = (h_g[M - 1] + 1.0f) * 0.5f;         // hs[M] (roll wrap)
    unsigned uM = (hsM < 1.0f && tid < NN - 1) ? 1u : 0u;
    unsigned dM = 0u;
    const unsigned int* p = UDt + tid;
    for (int k = 0; k < c; k += 32) {               // ILP-32; dup of last row is
        unsigned vv[32];                            // harmless (max idempotent)
        #pragma unroll
        for (int u = 0; u < 32; ++u) {
            int idx = k + u; if (idx >= c) idx = c - 1;
            vv[u] = p[idx * NN];
        }
        #pragma unroll
        for (int u = 0; u < 32; ++u) {
            unsigned ue = vv[u] & 0xFFFFu, de = vv[u] >> 16;
            if (ue > uM) uM = ue;
            if (de > dM) dM = de;
        }
    }
    int Ue = (int)uM;
    Dv[tid] = (int)dM;
    __syncthreads();

    // prefetch PrefT rows for each step's jh (coalesced)
    float pk[TT + 1];
    #pragma unroll
    for (int kk = 1; kk <= TT; ++kk) {
        int jh = (rec_s[kk] >> 11) & 0x1FF;
        pk[kk] = PrefT[jh * NN + tid];
    }

    // cix = #{j : De_j < Ue} (Dv non-decreasing), clamp to triangle
    int lo = 0, hi = NN;
    while (lo < hi) { int m = (lo + hi) >> 1; if (Dv[m] < Ue) lo = m + 1; else hi = m; }
    int cix = min(lo, tid + 1);
    float w = 2.0f * PrefT[cix * NN + tid] - RT;

    // barrier-free walk: per-thread deltas per step
    float vals[TT + 2];
    vals[0] = RT; vals[1] = w;
    int cc = cix; float ww = w;
    #pragma unroll
    for (int kk = 1; kk <= TT; ++kk) {
        float dl = 0.0f;
        if (kk <= Tb) {
            int rec = rec_s[kk];
            int d = rec & 3;
            if (d == 2) {                           // up: rows i < ih -> +RowTot
                int ih = (rec >> 2) & 0x1FF;
                if (tid < ih) { dl = RT - ww; ww = RT; cc = tid + 1; }
            } else if (d == 0) {                    // down: truncate prefix to jh
                int jh = (rec >> 11) & 0x1FF;
                if (cc > jh) { float wn = 2.0f * pk[kk] - RT; dl = wn - ww; ww = wn; cc = jh; }
            }
        }
        vals[1 + kk] = dl;
    }

    // reduce all TT+2 quantities: wave shuffle then cross-wave via LDS
    #pragma unroll
    for (int q = 0; q < TT + 2; ++q)
        for (int off = 32; off; off >>= 1)
            vals[q] += __shfl_down(vals[q], off, 64);
    int lane = tid & 63, wv = tid >> 6;
    if (lane == 0) {
        #pragma unroll
        for (int q = 0; q < TT + 2; ++q) red[wv * (TT + 2) + q] = vals[q];
    }
    __syncthreads();
    if (tid < TT + 2)
        tot[tid] = red[tid] + red[(TT + 2) + tid] + red[2 * (TT + 2) + tid] + red[3 * (TT + 2) + tid];
    __syncthreads();
    if (tid < TT) {                                 // 16-lane shuffle prefix-scan
        float x = tot[2 + tid];
        #pragma unroll
        for (int off = 1; off < TT; off <<= 1) {
            float y = __shfl_up(x, off, 64);
            if (tid >= off) x += y;
        }
        if (tid < Tb) out[t0 + tid] = (tot[1] + x) * (1.0f / tot[0]);
    }
}

extern "C" void kernel_launch(void* const* d_in, const int* in_sizes, int n_in,
                              void* d_out, int out_size, void* d_ws, size_t ws_size,
                              hipStream_t stream) {
    const float* h   = (const float*)d_in[0];
    const float* raw = (const float*)d_in[1];
    float* out = (float*)d_out;
    int M = in_sizes[0];            // 4000
    int G = (M + TT - 1) / TT;      // 250 chunks

    char* ws = (char*)d_ws;
    size_t off = 0;
    auto take = [&](size_t bytes) { size_t cur = off; off = (off + bytes + 255) & ~(size_t)255; return cur; };
    float*        PrefT  = (float*)(ws + take((size_t)(NN + 1) * NN * 4));
    float*        RowTot = (float*)(ws + take((size_t)NN * 4));
    int*          steps  = (int*)(ws + take((size_t)(M + 1) * 4));
    unsigned int* UDt    = (unsigned int*)(ws + take((size_t)G * NN * 4));

    int mode0 = 0;
    void* args[] = { (void*)&h, (void*)&raw, (void*)&out, (void*)&M, (void*)&G,
                     (void*)&PrefT, (void*)&RowTot, (void*)&steps, (void*)&UDt,
                     (void*)&mode0 };
    hipError_t e = hipLaunchCooperativeKernel((const void*)kMain, dim3(NN + G), dim3(256),
                                              args, 0, stream);
    if (e != hipSuccess) {
        (void)hipGetLastError();    // clear, fall back to two ordinary launches
        kMain<<<NN + G, 256, 0, stream>>>(h, raw, out, M, G, PrefT, RowTot, steps, UDt, 1);
        kMain<<<G,      256, 0, stream>>>(h, raw, out, M, G, PrefT, RowTot, steps, UDt, 2);
    }
}

// Round 5
// 75.825 us; speedup vs baseline: 1.9113x; 1.9113x over previous
//
#include <hip/hip_runtime.h>

#define NN 256     // Preisach mesh size
#define TT 16      // outputs (steps) per chunk; G = ceil(M/TT) = 250 for M=4000

__device__ __forceinline__ float softplus_f(float x) {
    if (x > 20.0f) return x;
    return log1pf(expf(x));
}

// ---- kA: 256 blocks, one row each: prefix sums of dens = softplus(raw)
//      on the lower triangle, stored transposed (PrefT[k][i], k=0..256).
__global__ void __launch_bounds__(256)
kA(const float* __restrict__ raw, float* __restrict__ PrefT, float* __restrict__ RowTot)
{
    __shared__ float wsum[4];
    int b = blockIdx.x, tid = threadIdx.x;
    float x = 0.0f;
    if (tid <= b) x = softplus_f(raw[b * (b + 1) / 2 + tid]);
    int lane = tid & 63, wv = tid >> 6;
    #pragma unroll
    for (int off = 1; off <= 32; off <<= 1) {      // intra-wave inclusive scan
        float y = __shfl_up(x, off, 64);
        if (lane >= off) x += y;
    }
    if (lane == 63) wsum[wv] = x;                  // wave totals
    __syncthreads();
    float add = 0.0f;
    if (wv > 0) add += wsum[0];
    if (wv > 1) add += wsum[1];
    if (wv > 2) add += wsum[2];
    x += add;
    PrefT[(tid + 1) * NN + b] = x;
    if (tid == 0)      PrefT[b] = 0.0f;
    if (tid == NN - 1) RowTot[b] = x;
}

// ---- kB: one block per 16-step chunk, fully self-sufficient carry.
//      Classify ALL steps tau <= t0+Tb from h (L2-resident, coalesced):
//      prior steps -> LDS atomicMax buckets; chunk steps -> rec_s.
//      Suffix/prefix-max scan -> per-row Ue / per-col De; then walk + reduce.
__global__ void __launch_bounds__(256)
kB(const float* __restrict__ h_g, const float* __restrict__ PrefT,
   const float* __restrict__ RowTot, float* __restrict__ out, int M)
{
    __shared__ float xs[NN];
    __shared__ int   bestU[NN + 1];    // bestU[ih] = last flip-time of up-steps at ih
    __shared__ int   bestD[NN + 1];    // bestD[jh] = last flip-time of down-steps at jh
    __shared__ int   rec_s[TT + 1];
    __shared__ float red[4 * (TT + 2)];
    __shared__ float tot[TT + 2];

    const int c   = blockIdx.x, tid = threadIdx.x;
    const int t0  = c * TT;
    const int Tb  = min(TT, M - t0);
    const int tmax = t0 + Tb;

    xs[tid] = (float)((double)tid / 255.0);        // np.linspace(0,1,256) f64->f32
    bestU[tid] = 0; bestD[tid] = 0;
    if (tid == 0) { bestU[NN] = 0; bestD[NN] = 0; }
    if (tid < TT) rec_s[1 + tid] = 0;
    __syncthreads();

    // classify steps (verified r1 P2): arithmetic seed + monotone advance
    for (int tau = 1 + tid; tau <= tmax; tau += NN) {
        float cur  = (h_g[tau - 1] + 1.0f) * 0.5f;
        float prev = (tau == 1) ? 1.0f : (h_g[tau - 2] + 1.0f) * 0.5f;
        int d = (cur > prev) ? 2 : ((cur < prev) ? 0 : 1);
        int g = (int)(cur * 255.0f) - 2;
        int ih = max(g, 0);
        while (ih < NN && xs[ih] < cur)  ++ih;     // ih = #{x < cur}
        int jh = ih;
        while (jh < NN && xs[jh] <= cur) ++jh;     // jh = #{x <= cur}
        if (tau <= t0) {
            if (d == 2)      atomicMax(&bestU[ih], tau + 1);  // up flips rows i < ih
            else if (d == 0) atomicMax(&bestD[jh], tau + 1);  // down clears cols j >= jh
        } else {
            rec_s[tau - t0] = d | (ih << 2) | (jh << 11);
        }
    }
    __syncthreads();

    // fused suffix-max(bestU) / prefix-max(bestD), in place (verified r1 P3)
    for (int off = 1; off <= NN; off <<= 1) {
        int vU = (tid + off <= NN) ? bestU[tid + off] : 0;
        int vD = (tid >= off)      ? bestD[tid - off] : 0;
        __syncthreads();
        if (vU > bestU[tid]) bestU[tid] = vU;
        if (vD > bestD[tid]) bestD[tid] = vD;
        __syncthreads();
    }
    // Ue(row tid) = max over up-steps with ih > tid (+ virtual tau=0 step, time=1)
    int Ue = bestU[tid + 1];
    float hsM = (h_g[M - 1] + 1.0f) * 0.5f;        // hs[M] (roll wrap)
    if (hsM < 1.0f && tid < NN - 1) Ue = max(Ue, 1);

    // cix = #{j : De[j] < Ue}; De = bestD (non-decreasing), clamp to triangle
    int lo = 0, hi = NN;
    while (lo < hi) { int m = (lo + hi) >> 1; if (bestD[m] < Ue) lo = m + 1; else hi = m; }
    int cix = min(lo, tid + 1);

    float RT = RowTot[tid];

    // prefetch PrefT rows for each step's jh (coalesced, verified r0)
    float pk[TT + 1];
    #pragma unroll
    for (int kk = 1; kk <= TT; ++kk) {
        int jh = (rec_s[kk] >> 11) & 0x1FF;
        pk[kk] = PrefT[jh * NN + tid];
    }
    float w = 2.0f * PrefT[cix * NN + tid] - RT;

    // barrier-free walk: per-thread deltas per step (verified r0/r3)
    float vals[TT + 2];
    vals[0] = RT; vals[1] = w;
    int cc = cix; float ww = w;
    #pragma unroll
    for (int kk = 1; kk <= TT; ++kk) {
        float dl = 0.0f;
        if (kk <= Tb) {
            int rec = rec_s[kk];
            int d = rec & 3;
            if (d == 2) {                          // up: rows i < ih -> +RowTot
                int ih = (rec >> 2) & 0x1FF;
                if (tid < ih) { dl = RT - ww; ww = RT; cc = tid + 1; }
            } else if (d == 0) {                   // down: truncate prefix to jh
                int jh = (rec >> 11) & 0x1FF;
                if (cc > jh) { float wn = 2.0f * pk[kk] - RT; dl = wn - ww; ww = wn; cc = jh; }
            }
        }
        vals[1 + kk] = dl;
    }

    // reduce all TT+2 quantities: wave shuffle then cross-wave via LDS
    #pragma unroll
    for (int q = 0; q < TT + 2; ++q)
        for (int off = 32; off; off >>= 1)
            vals[q] += __shfl_down(vals[q], off, 64);
    int lane = tid & 63, wv = tid >> 6;
    if (lane == 0) {
        #pragma unroll
        for (int q = 0; q < TT + 2; ++q) red[wv * (TT + 2) + q] = vals[q];
    }
    __syncthreads();
    if (tid < TT + 2)
        tot[tid] = red[tid] + red[(TT + 2) + tid] + red[2 * (TT + 2) + tid] + red[3 * (TT + 2) + tid];
    __syncthreads();
    if (tid < TT) {                                // 16-lane shuffle prefix-scan
        float x = tot[2 + tid];
        #pragma unroll
        for (int off = 1; off < TT; off <<= 1) {
            float y = __shfl_up(x, off, 64);
            if (tid >= off) x += y;
        }
        if (tid < Tb) out[t0 + tid] = (tot[1] + x) * (1.0f / tot[0]);
    }
}

extern "C" void kernel_launch(void* const* d_in, const int* in_sizes, int n_in,
                              void* d_out, int out_size, void* d_ws, size_t ws_size,
                              hipStream_t stream) {
    const float* h   = (const float*)d_in[0];
    const float* raw = (const float*)d_in[1];
    float* out = (float*)d_out;
    int M = in_sizes[0];            // 4000
    int G = (M + TT - 1) / TT;      // 250 chunks

    char* ws = (char*)d_ws;
    size_t off = 0;
    auto take = [&](size_t bytes) { size_t cur = off; off = (off + bytes + 255) & ~(size_t)255; return cur; };
    float* PrefT  = (float*)(ws + take((size_t)(NN + 1) * NN * 4));
    float* RowTot = (float*)(ws + take((size_t)NN * 4));

    kA<<<NN, 256, 0, stream>>>(raw, PrefT, RowTot);
    kB<<<G,  256, 0, stream>>>(h, PrefT, RowTot, out, M);
}